// Round 8
// baseline (457.670 us; speedup 1.0000x reference)
//
#include <hip/hip_runtime.h>

typedef unsigned short u16;
using bf16x8 = __attribute__((ext_vector_type(8))) __bf16;
using f32x4  = __attribute__((ext_vector_type(4))) float;
using s16x8  = __attribute__((ext_vector_type(8))) short;
using s16x4  = __attribute__((ext_vector_type(4))) short;

#define AS1 __attribute__((address_space(1)))
#define AS3 __attribute__((address_space(3)))

__device__ __forceinline__ void gload16(const u16* g, u16* l) {
  __builtin_amdgcn_global_load_lds((AS1 void*)(size_t)g, (AS3 void*)l, 16, 0, 0);
}

__device__ __forceinline__ u16 f2bf(float f) {
  unsigned u = __float_as_uint(f);
  u += 0x7fffu + ((u >> 16) & 1u);   // round-to-nearest-even
  return (u16)(u >> 16);
}
__device__ __forceinline__ float bf2f(u16 h) {
  return __uint_as_float(((unsigned)h) << 16);
}

// ---------------- elementwise f32 -> bf16 ----------------
__global__ __launch_bounds__(256) void cast_bf16_kernel(const float* __restrict__ x,
                                                        u16* __restrict__ y, int n) {
  int i = (blockIdx.x * 256 + threadIdx.x) * 4;
  if (i + 3 < n) {
    float4 v = *reinterpret_cast<const float4*>(x + i);
    s16x4 o;
    o[0] = (short)f2bf(v.x); o[1] = (short)f2bf(v.y);
    o[2] = (short)f2bf(v.z); o[3] = (short)f2bf(v.w);
    *reinterpret_cast<s16x4*>(y + i) = o;
  }
}

// ---------------- W [K][N] f32 -> WT [N][K] bf16 (64x64 tiles) ----------------
__global__ __launch_bounds__(256) void transpose_cast_kernel(const float* __restrict__ W,
                                                             u16* __restrict__ WT,
                                                             int K, int N) {
  __shared__ u16 tile[64][72];
  const int t = threadIdx.x;
  const int nb = blockIdx.x * 64, kb = blockIdx.y * 64;
  const int rr = t >> 3;        // 0..31
  const int cc = (t & 7) * 8;   // 0..56
#pragma unroll
  for (int pass = 0; pass < 2; ++pass) {
    const float* src = W + (size_t)(kb + pass * 32 + rr) * N + nb + cc;
    float4 a = *reinterpret_cast<const float4*>(src);
    float4 b = *reinterpret_cast<const float4*>(src + 4);
    u16* tr = &tile[pass * 32 + rr][cc];
    tr[0] = f2bf(a.x); tr[1] = f2bf(a.y); tr[2] = f2bf(a.z); tr[3] = f2bf(a.w);
    tr[4] = f2bf(b.x); tr[5] = f2bf(b.y); tr[6] = f2bf(b.z); tr[7] = f2bf(b.w);
  }
  __syncthreads();
#pragma unroll
  for (int pass = 0; pass < 2; ++pass) {
    s16x8 v;
#pragma unroll
    for (int j = 0; j < 8; ++j) v[j] = (short)tile[cc + j][pass * 32 + rr];
    *reinterpret_cast<s16x8*>(WT + (size_t)(nb + pass * 32 + rr) * K + kb + cc) = v;
  }
}

// ---------------- RMSNorm (bf16 in/out, f32 weight) ----------------
__global__ __launch_bounds__(256) void rmsnorm_kernel(const u16* __restrict__ x,
                                                      const float* __restrict__ w,
                                                      u16* __restrict__ y,
                                                      int R, int xs, int ys) {
  const int row = blockIdx.x, t = threadIdx.x;
  const u16* xr = x + (size_t)row * xs;
  float ss = 0.f;
  for (int i = t; i < R; i += 256) { float f = bf2f(xr[i]); ss += f * f; }
#pragma unroll
  for (int m = 32; m >= 1; m >>= 1) ss += __shfl_xor(ss, m);
  __shared__ float red[4];
  if ((t & 63) == 0) red[t >> 6] = ss;
  __syncthreads();
  float tot = red[0] + red[1] + red[2] + red[3];
  float r = rsqrtf(tot / (float)R + 1e-6f);
  u16* yr = y + (size_t)row * ys;
  for (int i = t; i < R; i += 256) yr[i] = f2bf(bf2f(xr[i]) * r * w[i]);
}

// ---------------- RoPE cos/sin table: [2048][32] each ----------------
__global__ __launch_bounds__(256) void rope_table_kernel(float* __restrict__ cost,
                                                         float* __restrict__ sint) {
  int idx = blockIdx.x * 256 + threadIdx.x;   // 65536
  int pos = idx >> 5, j = idx & 31;
  float inv = __expf(-(float)j * (9.210340371976184f / 32.0f));  // 10000^(-j/32)
  float f = (float)pos * inv;
  cost[idx] = cosf(f);
  sint[idx] = sinf(f);
}

// ---------------- qf build (vectorized): q [s][h*192] -> qf [h][s][192], RoPE + scale ----------------
__global__ __launch_bounds__(256) void build_qf_kernel(const u16* __restrict__ q,
                                                       const float* __restrict__ cost,
                                                       const float* __restrict__ sint,
                                                       u16* __restrict__ qf) {
  int tid = blockIdx.x * 256 + threadIdx.x;
  int o8 = tid * 8;
  if (o8 >= 32 * 2048 * 192) return;
  const float scale = 0.07216878364870323f;  // 192^-0.5 (folded into q)
  int c = (o8 % 192) >> 3;  // chunk 0..23
  int rest = o8 / 192;
  int s = rest & 2047, h = rest >> 11;
  const u16* qrow = q + ((size_t)s * 32 + h) * 192;
  s16x8 out;
  if (c < 16) {
    s16x8 v = *reinterpret_cast<const s16x8*>(qrow + c * 8);
#pragma unroll
    for (int j = 0; j < 8; ++j) out[j] = (short)f2bf(bf2f((u16)v[j]) * scale);
  } else {
    int j0 = c * 8 - 128;
    bool lo = j0 < 32;
    int jj0 = lo ? j0 : j0 - 32;
    s16x8 a = *reinterpret_cast<const s16x8*>(qrow + 128 + 2 * jj0);
    s16x8 b = *reinterpret_cast<const s16x8*>(qrow + 128 + 2 * jj0 + 8);
    float4 c0 = *reinterpret_cast<const float4*>(cost + s * 32 + jj0);
    float4 c1 = *reinterpret_cast<const float4*>(cost + s * 32 + jj0 + 4);
    float4 s0 = *reinterpret_cast<const float4*>(sint + s * 32 + jj0);
    float4 s1 = *reinterpret_cast<const float4*>(sint + s * 32 + jj0 + 4);
    float cs[8] = {c0.x, c0.y, c0.z, c0.w, c1.x, c1.y, c1.z, c1.w};
    float sn[8] = {s0.x, s0.y, s0.z, s0.w, s1.x, s1.y, s1.z, s1.w};
#pragma unroll
    for (int j = 0; j < 8; ++j) {
      float x0 = bf2f((u16)((j < 4) ? a[2 * j] : b[2 * j - 8]));
      float x1 = bf2f((u16)((j < 4) ? a[2 * j + 1] : b[2 * j - 7]));
      float v = lo ? (x0 * cs[j] - x1 * sn[j]) : (x1 * cs[j] + x0 * sn[j]);
      out[j] = (short)f2bf(v * scale);
    }
  }
  *reinterpret_cast<s16x8*>(qf + o8) = out;
}

// ---------------- kf build (vectorized): kv [s][h*256], ckv(stride 2112) -> kf [h][s][192] ----------------
__global__ __launch_bounds__(256) void build_kf_kernel(const u16* __restrict__ kv,
                                                       const u16* __restrict__ ckv,
                                                       const float* __restrict__ cost,
                                                       const float* __restrict__ sint,
                                                       u16* __restrict__ kf) {
  int tid = blockIdx.x * 256 + threadIdx.x;
  int o8 = tid * 8;
  if (o8 >= 32 * 2048 * 192) return;
  int c = (o8 % 192) >> 3;
  int rest = o8 / 192;
  int s = rest & 2047, h = rest >> 11;
  s16x8 out;
  if (c < 16) {
    out = *reinterpret_cast<const s16x8*>(kv + ((size_t)s * 32 + h) * 256 + c * 8);
  } else {
    int j0 = c * 8 - 128;
    bool lo = j0 < 32;
    int jj0 = lo ? j0 : j0 - 32;
    const u16* crow = ckv + (size_t)s * 2112 + 512;
    s16x8 a = *reinterpret_cast<const s16x8*>(crow + 2 * jj0);
    s16x8 b = *reinterpret_cast<const s16x8*>(crow + 2 * jj0 + 8);
    float4 c0 = *reinterpret_cast<const float4*>(cost + s * 32 + jj0);
    float4 c1 = *reinterpret_cast<const float4*>(cost + s * 32 + jj0 + 4);
    float4 s0 = *reinterpret_cast<const float4*>(sint + s * 32 + jj0);
    float4 s1 = *reinterpret_cast<const float4*>(sint + s * 32 + jj0 + 4);
    float cs[8] = {c0.x, c0.y, c0.z, c0.w, c1.x, c1.y, c1.z, c1.w};
    float sn[8] = {s0.x, s0.y, s0.z, s0.w, s1.x, s1.y, s1.z, s1.w};
#pragma unroll
    for (int j = 0; j < 8; ++j) {
      float x0 = bf2f((u16)((j < 4) ? a[2 * j] : b[2 * j - 8]));
      float x1 = bf2f((u16)((j < 4) ? a[2 * j + 1] : b[2 * j - 7]));
      float v = lo ? (x0 * cs[j] - x1 * sn[j]) : (x1 * cs[j] + x0 * sn[j]);
      out[j] = (short)f2bf(v);
    }
  }
  *reinterpret_cast<s16x8*>(kf + o8) = out;
}

// ---------------- vT build: kv [s][h*256+128+d] -> vT [h][128][2048] ----------------
__global__ __launch_bounds__(256) void vt_build_kernel(const u16* __restrict__ kv,
                                                       u16* __restrict__ vT) {
  __shared__ u16 tile[64][72];
  const int t = threadIdx.x;
  const int sb = blockIdx.x * 64, db = blockIdx.y * 64, h = blockIdx.z;
  const int rr = t >> 3, cc = (t & 7) * 8;
#pragma unroll
  for (int pass = 0; pass < 2; ++pass) {
    const u16* src = kv + (size_t)(sb + pass * 32 + rr) * 8192 + h * 256 + 128 + db + cc;
    s16x8 v = *reinterpret_cast<const s16x8*>(src);
#pragma unroll
    for (int j = 0; j < 8; ++j) tile[pass * 32 + rr][cc + j] = (u16)v[j];
  }
  __syncthreads();
#pragma unroll
  for (int pass = 0; pass < 2; ++pass) {
    s16x8 v;
#pragma unroll
    for (int j = 0; j < 8; ++j) v[j] = (short)tile[cc + j][pass * 32 + rr];
    *reinterpret_cast<s16x8*>(vT + ((size_t)h * 128 + db + pass * 32 + rr) * 2048 + sb + cc) = v;
  }
}

// ---------------- GEMM v3: C[M][N] = A[M][K](bf16) * BT[N][K](bf16)^T ----------------
// 128x128 tile, BK=32, 4 waves (2x2). 4-deep LDS pipeline, prefetch distance 3,
// one raw s_barrier/iter with counted vmcnt(8), XOR-swizzled LDS, setprio MFMA.
template <int OUT_BF16>
__global__ __launch_bounds__(256) void gemm_v3_kernel(const u16* __restrict__ A,
                                                      const u16* __restrict__ BT,
                                                      void* __restrict__ Cv,
                                                      int M, int N, int K) {
  __shared__ __align__(16) u16 S[4 * 8192];
  const int t0 = threadIdx.x;
  const int lane = t0 & 63, wave = t0 >> 6;
  const int wr = wave >> 1, wc = wave & 1;
  const int row0 = blockIdx.y * 128, col0 = blockIdx.x * 128;
  const int lrow = lane & 15, lkg = lane >> 4;

  const int lp = lane ^ ((lane >> 3) & 3);
  const int srow_off = lp >> 2;
  const int skel = (lp & 3) * 8;
  const int c0 = wave * 2, c1 = c0 + 1;
  const int arow_c0 = row0 + c0 * 16 + srow_off;
  const int arow_c1 = row0 + c1 * 16 + srow_off;
  int brow_c0 = col0 + c0 * 16 + srow_off; if (brow_c0 > N - 1) brow_c0 = N - 1;
  int brow_c1 = col0 + c1 * 16 + srow_off; if (brow_c1 > N - 1) brow_c1 = N - 1;

  int aoff[4], boff[4];
#pragma unroll
  for (int m = 0; m < 4; ++m) {
    int r = wr * 64 + m * 16 + lrow;
    int off = r * 32 + lkg * 8;
    aoff[m] = off ^ ((off >> 3) & 0x18);
    r = wc * 64 + m * 16 + lrow;
    off = r * 32 + lkg * 8;
    boff[m] = off ^ ((off >> 3) & 0x18);
  }

  const int NT = K >> 5;

#pragma unroll
  for (int pt = 0; pt < 3; ++pt) {
    u16* ab = &S[pt * 8192];
    const int kb = pt * 32 + skel;
    gload16(A  + (size_t)arow_c0 * K + kb, ab + c0 * 512);
    gload16(A  + (size_t)arow_c1 * K + kb, ab + c1 * 512);
    gload16(BT + (size_t)brow_c0 * K + kb, ab + 4096 + c0 * 512);
    gload16(BT + (size_t)brow_c1 * K + kb, ab + 4096 + c1 * 512);
  }

  f32x4 acc[4][4];
#pragma unroll
  for (int m = 0; m < 4; ++m)
#pragma unroll
    for (int n = 0; n < 4; ++n) acc[m][n] = 0.f;

  for (int t = 0; t < NT; ++t) {
    if (t + 2 < NT)      asm volatile("s_waitcnt vmcnt(8)" ::: "memory");
    else if (t + 1 < NT) asm volatile("s_waitcnt vmcnt(4)" ::: "memory");
    else                 asm volatile("s_waitcnt vmcnt(0)" ::: "memory");
    __builtin_amdgcn_s_barrier();
    __builtin_amdgcn_sched_barrier(0);

    const u16* ab = &S[(t & 3) * 8192];
    bf16x8 af[4], bb[4];
#pragma unroll
    for (int m = 0; m < 4; ++m)
      af[m] = *reinterpret_cast<const bf16x8*>(ab + aoff[m]);
#pragma unroll
    for (int n = 0; n < 4; ++n)
      bb[n] = *reinterpret_cast<const bf16x8*>(ab + 4096 + boff[n]);

    if (t + 3 < NT) {
      u16* sb = &S[((t + 3) & 3) * 8192];
      const int kb = (t + 3) * 32 + skel;
      gload16(A  + (size_t)arow_c0 * K + kb, sb + c0 * 512);
      gload16(A  + (size_t)arow_c1 * K + kb, sb + c1 * 512);
      gload16(BT + (size_t)brow_c0 * K + kb, sb + 4096 + c0 * 512);
      gload16(BT + (size_t)brow_c1 * K + kb, sb + 4096 + c1 * 512);
    }

    __builtin_amdgcn_s_setprio(1);
#pragma unroll
    for (int m = 0; m < 4; ++m)
#pragma unroll
      for (int n = 0; n < 4; ++n)
        acc[m][n] = __builtin_amdgcn_mfma_f32_16x16x32_bf16(af[m], bb[n], acc[m][n], 0, 0, 0);
    __builtin_amdgcn_s_setprio(0);
  }

#pragma unroll
  for (int m = 0; m < 4; ++m) {
#pragma unroll
    for (int n = 0; n < 4; ++n) {
      int col = col0 + wc * 64 + n * 16 + lrow;
      if (col < N) {
#pragma unroll
        for (int i = 0; i < 4; ++i) {
          int row = row0 + wr * 64 + m * 16 + lkg * 4 + i;
          size_t idx = (size_t)row * N + col;
          if (OUT_BF16) ((u16*)Cv)[idx] = f2bf(acc[m][n][i]);
          else          ((float*)Cv)[idx] = acc[m][n][i];
        }
      }
    }
  }
}

// ---------------- causal flash attention v2: 2 waves x 32 q-rows, heavy-first ----------------
// grid (h=32, qy=32): qb = 31-qy (heavy-first; queue exists since LDS caps 3 blocks/CU).
// bid%8 = h%8 -> XCD head-pinning. 128 thr = 2 waves; wave w owns rows qb*64+w*32..+32
// as two 16-row halves -> each K/V LDS fragment feeds 2 MFMAs (halved LDS/FLOP).
// Single-buffer 49KB LDS (Kt 24K + Vt 16K + Pl 9K), K/V staged in fragment order via
// global_load_lds. T13 defer-max (skip rescale unless tmax > m_run+8) + deferred-l
// (per-lane partial l, one epilogue reduce).
__global__ __launch_bounds__(128) void mla_attn_kernel(const u16* __restrict__ qf,
                                                       const u16* __restrict__ kf,
                                                       const u16* __restrict__ vT,
                                                       u16* __restrict__ o) {
  const int h = blockIdx.x, qb = 31 - blockIdx.y;
  const int t = threadIdx.x, wave = t >> 6, lane = t & 63;
  const int lrow = lane & 15, lkg = lane >> 4;
  __shared__ __align__(16) u16 Kt[24 * 512];   // (cg,kk): K[cg*16+l&15][kk*32+(l>>4)*8]
  __shared__ __align__(16) u16 Vt[16 * 512];   // (f,ck):  vT[f*16+l&15][ck*32+(l>>4)*8]
  __shared__ __align__(16) u16 Pl[2][32][72];

  // staging: wave w stages K cgs {2w,2w+1} (12 chunks) and V f-rows {4w..4w+3} (8 chunks)
  const u16* ksrcA = kf + ((size_t)h * 2048 + (2 * wave) * 16 + lrow) * 192 + lkg * 8;
  const u16* ksrcB = ksrcA + (size_t)16 * 192;
  const u16* vsrc0 = vT + ((size_t)h * 128 + (4 * wave) * 16 + lrow) * 2048 + lkg * 8;

  const int qbase = qb * 64 + wave * 32;

  // Q fragments: 2 row-halves x 6 k-chunks
  bf16x8 qfr[2][6];
#pragma unroll
  for (int r = 0; r < 2; ++r) {
    const u16* qp = qf + ((size_t)h * 2048 + qbase + r * 16 + lrow) * 192 + lkg * 8;
#pragma unroll
    for (int kk = 0; kk < 6; ++kk)
      qfr[r][kk] = *reinterpret_cast<const bf16x8*>(qp + kk * 32);
  }

  f32x4 acc[2][8];
#pragma unroll
  for (int r = 0; r < 2; ++r)
#pragma unroll
    for (int f = 0; f < 8; ++f) acc[r][f] = 0.f;
  float m_run[2][4], l_par[2][4];
#pragma unroll
  for (int r = 0; r < 2; ++r)
#pragma unroll
    for (int i = 0; i < 4; ++i) { m_run[r][i] = -1e30f; l_par[r][i] = 0.f; }

  const int kv_end = qb * 64 + 64;
  for (int kt = 0; kt < kv_end; kt += 64) {
    // ---- stage K (12 chunks) + V (8 chunks) for this wave ----
    {
      const u16* ka = ksrcA + (size_t)kt * 192;
      const u16* kb = ksrcB + (size_t)kt * 192;
#pragma unroll
      for (int kk = 0; kk < 6; ++kk) {
        gload16(ka + kk * 32, &Kt[((2 * wave) * 6 + kk) * 512]);
        gload16(kb + kk * 32, &Kt[((2 * wave + 1) * 6 + kk) * 512]);
      }
#pragma unroll
      for (int j = 0; j < 4; ++j) {
#pragma unroll
        for (int ck = 0; ck < 2; ++ck)
          gload16(vsrc0 + (size_t)j * 16 * 2048 + kt + ck * 32,
                  &Vt[((4 * wave + j) * 2 + ck) * 512]);
      }
    }
    __syncthreads();

    // ---- S = Q K^T: 48 MFMA on 24 K-fragment reads (2x reuse) ----
    f32x4 sv[2][4];
#pragma unroll
    for (int r = 0; r < 2; ++r)
#pragma unroll
      for (int cg = 0; cg < 4; ++cg) sv[r][cg] = 0.f;
#pragma unroll
    for (int cg = 0; cg < 4; ++cg)
#pragma unroll
      for (int kk = 0; kk < 6; ++kk) {
        bf16x8 kfr = *reinterpret_cast<const bf16x8*>(&Kt[(cg * 6 + kk) * 512 + lane * 8]);
        sv[0][cg] = __builtin_amdgcn_mfma_f32_16x16x32_bf16(qfr[0][kk], kfr, sv[0][cg], 0, 0, 0);
        sv[1][cg] = __builtin_amdgcn_mfma_f32_16x16x32_bf16(qfr[1][kk], kfr, sv[1][cg], 0, 0, 0);
      }

    // ---- causal mask (diagonal tile only) ----
    if (kt + 64 >= kv_end) {
#pragma unroll
      for (int r = 0; r < 2; ++r)
#pragma unroll
        for (int cg = 0; cg < 4; ++cg) {
          int kvcol = kt + cg * 16 + lrow;
          int rowb = qbase + r * 16 + lkg * 4;
#pragma unroll
          for (int i = 0; i < 4; ++i)
            if (kvcol > rowb + i) sv[r][cg][i] = -__builtin_inff();
        }
    }

    // ---- online softmax per row-half: defer-max + deferred-l ----
#pragma unroll
    for (int r = 0; r < 2; ++r) {
      float tmax[4];
#pragma unroll
      for (int i = 0; i < 4; ++i)
        tmax[i] = fmaxf(fmaxf(sv[r][0][i], sv[r][1][i]), fmaxf(sv[r][2][i], sv[r][3][i]));
#pragma unroll
      for (int m = 8; m >= 1; m >>= 1)
#pragma unroll
        for (int i = 0; i < 4; ++i) tmax[i] = fmaxf(tmax[i], __shfl_xor(tmax[i], m));
      int need = 0;
#pragma unroll
      for (int i = 0; i < 4; ++i) need |= (tmax[i] > m_run[r][i] + 8.f) ? 1 : 0;
      if (__any(need)) {
#pragma unroll
        for (int i = 0; i < 4; ++i) {
          float mnew = fmaxf(m_run[r][i], tmax[i]);
          float alpha = __expf(m_run[r][i] - mnew);
          m_run[r][i] = mnew;
          l_par[r][i] *= alpha;
#pragma unroll
          for (int f = 0; f < 8; ++f) acc[r][f][i] *= alpha;
        }
      }
#pragma unroll
      for (int i = 0; i < 4; ++i) {
#pragma unroll
        for (int cg = 0; cg < 4; ++cg) sv[r][cg][i] = __expf(sv[r][cg][i] - m_run[r][i]);
        l_par[r][i] += (sv[r][0][i] + sv[r][1][i]) + (sv[r][2][i] + sv[r][3][i]);
      }
      // P -> bf16 -> per-wave LDS
#pragma unroll
      for (int cg = 0; cg < 4; ++cg)
#pragma unroll
        for (int i = 0; i < 4; ++i)
          Pl[wave][r * 16 + lkg * 4 + i][cg * 16 + lrow] = f2bf(sv[r][cg][i]);
    }

    // ---- O += P V: 32 MFMA on 16 V-fragment reads (2x reuse) ----
#pragma unroll
    for (int ck = 0; ck < 2; ++ck) {
      bf16x8 pf0 = *reinterpret_cast<const bf16x8*>(&Pl[wave][lrow][ck * 32 + lkg * 8]);
      bf16x8 pf1 = *reinterpret_cast<const bf16x8*>(&Pl[wave][16 + lrow][ck * 32 + lkg * 8]);
#pragma unroll
      for (int f = 0; f < 8; ++f) {
        bf16x8 vfr = *reinterpret_cast<const bf16x8*>(&Vt[(f * 2 + ck) * 512 + lane * 8]);
        acc[0][f] = __builtin_amdgcn_mfma_f32_16x16x32_bf16(pf0, vfr, acc[0][f], 0, 0, 0);
        acc[1][f] = __builtin_amdgcn_mfma_f32_16x16x32_bf16(pf1, vfr, acc[1][f], 0, 0, 0);
      }
    }
    __syncthreads();   // all waves done reading Kt/Vt before next stage
  }

  // ---- epilogue: one l reduce, divide, store ----
#pragma unroll
  for (int r = 0; r < 2; ++r)
#pragma unroll
    for (int i = 0; i < 4; ++i) {
#pragma unroll
      for (int m = 8; m >= 1; m >>= 1) l_par[r][i] += __shfl_xor(l_par[r][i], m);
    }
#pragma unroll
  for (int r = 0; r < 2; ++r)
#pragma unroll
    for (int f = 0; f < 8; ++f)
#pragma unroll
      for (int i = 0; i < 4; ++i) {
        int row = qbase + r * 16 + lkg * 4 + i;
        int col = h * 128 + f * 16 + lrow;
        o[(size_t)row * 4096 + col] = f2bf(acc[r][f][i] / l_par[r][i]);
      }
}

// ---------------------------------------------------------------
extern "C" void kernel_launch(void* const* d_in, const int* in_sizes, int n_in,
                              void* d_out, int out_size, void* d_ws, size_t ws_size,
                              hipStream_t stream) {
  (void)in_sizes; (void)n_in; (void)out_size; (void)ws_size;
  const float* hs   = (const float*)d_in[0];
  const float* Wqa  = (const float*)d_in[1];
  const float* qln  = (const float*)d_in[2];
  const float* Wqb  = (const float*)d_in[3];
  const float* Wkva = (const float*)d_in[4];
  const float* kvln = (const float*)d_in[5];
  const float* Wkvb = (const float*)d_in[6];
  const float* Wo   = (const float*)d_in[7];
  float* out = (float*)d_out;

  char* p = (char*)d_ws;
  size_t off = 0;
  auto carve = [&](size_t bytes) {
    char* r = p + off;
    off += (bytes + 255) & ~(size_t)255;
    return r;
  };
  u16* hs_bf = (u16*)carve((size_t)2048 * 4096 * 2);
  u16* WabT  = (u16*)carve((size_t)2112 * 4096 * 2);   // [0..1535]=WqaT, [1536..2111]=WkvaT
  u16* WqbT  = (u16*)carve((size_t)6144 * 1536 * 2);
  u16* WkvbT = (u16*)carve((size_t)8192 * 512 * 2);
  u16* WoT   = (u16*)carve((size_t)4096 * 4096 * 2);
  u16* fused = (u16*)carve((size_t)2048 * 2112 * 2);   // [qa | ckv] per row
  u16* qan   = (u16*)carve((size_t)2048 * 1536 * 2);
  u16* q     = (u16*)carve((size_t)2048 * 6144 * 2);
  u16* cn    = (u16*)carve((size_t)2048 * 512 * 2);
  u16* kv    = (u16*)carve((size_t)2048 * 8192 * 2);
  u16* qfb   = (u16*)carve((size_t)32 * 2048 * 192 * 2);
  u16* kfb   = (u16*)carve((size_t)32 * 2048 * 192 * 2);
  u16* vTb   = (u16*)carve((size_t)32 * 128 * 2048 * 2);
  u16* ob    = (u16*)carve((size_t)2048 * 4096 * 2);
  float* cost = (float*)carve((size_t)65536 * 4);
  float* sint = (float*)carve((size_t)65536 * 4);

  // --- prep: casts / transposes / tables ---
  cast_bf16_kernel<<<8192, 256, 0, stream>>>(hs, hs_bf, 2048 * 4096);
  transpose_cast_kernel<<<dim3(24, 64), 256, 0, stream>>>(Wqa, WabT, 4096, 1536);
  transpose_cast_kernel<<<dim3(9, 64), 256, 0, stream>>>(Wkva, WabT + (size_t)1536 * 4096, 4096, 576);
  transpose_cast_kernel<<<dim3(96, 24), 256, 0, stream>>>(Wqb, WqbT, 1536, 6144);
  transpose_cast_kernel<<<dim3(128, 8), 256, 0, stream>>>(Wkvb, WkvbT, 512, 8192);
  transpose_cast_kernel<<<dim3(64, 64), 256, 0, stream>>>(Wo, WoT, 4096, 4096);
  rope_table_kernel<<<256, 256, 0, stream>>>(cost, sint);

  // --- fused first-stage GEMM: [qa | ckv] = hs @ [Wqa | Wkva] ---
  gemm_v3_kernel<1><<<dim3(17, 16), 256, 0, stream>>>(hs_bf, WabT, fused, 2048, 2112, 4096);

  // --- norms ---
  rmsnorm_kernel<<<2048, 256, 0, stream>>>(fused, qln, qan, 1536, 2112, 1536);
  rmsnorm_kernel<<<2048, 256, 0, stream>>>(fused + 1536, kvln, cn, 512, 2112, 512);

  // --- second-stage GEMMs ---
  gemm_v3_kernel<1><<<dim3(48, 16), 256, 0, stream>>>(qan, WqbT, q, 2048, 6144, 1536);
  gemm_v3_kernel<1><<<dim3(64, 16), 256, 0, stream>>>(cn, WkvbT, kv, 2048, 8192, 512);

  // --- head-major layouts + RoPE (vectorized) ---
  build_qf_kernel<<<6144, 256, 0, stream>>>(q, cost, sint, qfb);
  build_kf_kernel<<<6144, 256, 0, stream>>>(kv, fused + 1536, cost, sint, kfb);
  vt_build_kernel<<<dim3(32, 2, 32), 256, 0, stream>>>(kv, vTb);

  // --- attention (1024 blocks of 128 thr, heavy-first, 3/CU, head-pinned) ---
  mla_attn_kernel<<<dim3(32, 32), 128, 0, stream>>>(qfb, kfb, vTb, ob);

  // --- output projection ---
  gemm_v3_kernel<0><<<dim3(32, 16), 256, 0, stream>>>(ob, WoT, out, 2048, 4096, 4096);
}

// Round 9
// 434.408 us; speedup vs baseline: 1.0535x; 1.0535x over previous
//
#include <hip/hip_runtime.h>

typedef unsigned short u16;
using bf16x8 = __attribute__((ext_vector_type(8))) __bf16;
using f32x4  = __attribute__((ext_vector_type(4))) float;
using s16x8  = __attribute__((ext_vector_type(8))) short;
using s16x4  = __attribute__((ext_vector_type(4))) short;

#define AS1 __attribute__((address_space(1)))
#define AS3 __attribute__((address_space(3)))

__device__ __forceinline__ void gload16(const u16* g, u16* l) {
  __builtin_amdgcn_global_load_lds((AS1 void*)(size_t)g, (AS3 void*)l, 16, 0, 0);
}

__device__ __forceinline__ u16 f2bf(float f) {
  unsigned u = __float_as_uint(f);
  u += 0x7fffu + ((u >> 16) & 1u);   // round-to-nearest-even
  return (u16)(u >> 16);
}
__device__ __forceinline__ float bf2f(u16 h) {
  return __uint_as_float(((unsigned)h) << 16);
}

// ---------------- elementwise f32 -> bf16 ----------------
__global__ __launch_bounds__(256) void cast_bf16_kernel(const float* __restrict__ x,
                                                        u16* __restrict__ y, int n) {
  int i = (blockIdx.x * 256 + threadIdx.x) * 4;
  if (i + 3 < n) {
    float4 v = *reinterpret_cast<const float4*>(x + i);
    s16x4 o;
    o[0] = (short)f2bf(v.x); o[1] = (short)f2bf(v.y);
    o[2] = (short)f2bf(v.z); o[3] = (short)f2bf(v.w);
    *reinterpret_cast<s16x4*>(y + i) = o;
  }
}

// ---------------- W [K][N] f32 -> WT [N][K] bf16 (64x64 tiles) ----------------
__global__ __launch_bounds__(256) void transpose_cast_kernel(const float* __restrict__ W,
                                                             u16* __restrict__ WT,
                                                             int K, int N) {
  __shared__ u16 tile[64][72];
  const int t = threadIdx.x;
  const int nb = blockIdx.x * 64, kb = blockIdx.y * 64;
  const int rr = t >> 3;        // 0..31
  const int cc = (t & 7) * 8;   // 0..56
#pragma unroll
  for (int pass = 0; pass < 2; ++pass) {
    const float* src = W + (size_t)(kb + pass * 32 + rr) * N + nb + cc;
    float4 a = *reinterpret_cast<const float4*>(src);
    float4 b = *reinterpret_cast<const float4*>(src + 4);
    u16* tr = &tile[pass * 32 + rr][cc];
    tr[0] = f2bf(a.x); tr[1] = f2bf(a.y); tr[2] = f2bf(a.z); tr[3] = f2bf(a.w);
    tr[4] = f2bf(b.x); tr[5] = f2bf(b.y); tr[6] = f2bf(b.z); tr[7] = f2bf(b.w);
  }
  __syncthreads();
#pragma unroll
  for (int pass = 0; pass < 2; ++pass) {
    s16x8 v;
#pragma unroll
    for (int j = 0; j < 8; ++j) v[j] = (short)tile[cc + j][pass * 32 + rr];
    *reinterpret_cast<s16x8*>(WT + (size_t)(nb + pass * 32 + rr) * K + kb + cc) = v;
  }
}

// ---------------- RMSNorm (bf16 in/out, f32 weight) ----------------
__global__ __launch_bounds__(256) void rmsnorm_kernel(const u16* __restrict__ x,
                                                      const float* __restrict__ w,
                                                      u16* __restrict__ y,
                                                      int R, int xs, int ys) {
  const int row = blockIdx.x, t = threadIdx.x;
  const u16* xr = x + (size_t)row * xs;
  float ss = 0.f;
  for (int i = t; i < R; i += 256) { float f = bf2f(xr[i]); ss += f * f; }
#pragma unroll
  for (int m = 32; m >= 1; m >>= 1) ss += __shfl_xor(ss, m);
  __shared__ float red[4];
  if ((t & 63) == 0) red[t >> 6] = ss;
  __syncthreads();
  float tot = red[0] + red[1] + red[2] + red[3];
  float r = rsqrtf(tot / (float)R + 1e-6f);
  u16* yr = y + (size_t)row * ys;
  for (int i = t; i < R; i += 256) yr[i] = f2bf(bf2f(xr[i]) * r * w[i]);
}

// ---------------- RoPE cos/sin table: [2048][32] each ----------------
__global__ __launch_bounds__(256) void rope_table_kernel(float* __restrict__ cost,
                                                         float* __restrict__ sint) {
  int idx = blockIdx.x * 256 + threadIdx.x;   // 65536
  int pos = idx >> 5, j = idx & 31;
  float inv = __expf(-(float)j * (9.210340371976184f / 32.0f));  // 10000^(-j/32)
  float f = (float)pos * inv;
  cost[idx] = cosf(f);
  sint[idx] = sinf(f);
}

// ---------------- qf build (vectorized): q [s][h*192] -> qf [h][s][192], RoPE + scale ----------------
__global__ __launch_bounds__(256) void build_qf_kernel(const u16* __restrict__ q,
                                                       const float* __restrict__ cost,
                                                       const float* __restrict__ sint,
                                                       u16* __restrict__ qf) {
  int tid = blockIdx.x * 256 + threadIdx.x;
  int o8 = tid * 8;
  if (o8 >= 32 * 2048 * 192) return;
  const float scale = 0.07216878364870323f;  // 192^-0.5 (folded into q)
  int c = (o8 % 192) >> 3;  // chunk 0..23
  int rest = o8 / 192;
  int s = rest & 2047, h = rest >> 11;
  const u16* qrow = q + ((size_t)s * 32 + h) * 192;
  s16x8 out;
  if (c < 16) {
    s16x8 v = *reinterpret_cast<const s16x8*>(qrow + c * 8);
#pragma unroll
    for (int j = 0; j < 8; ++j) out[j] = (short)f2bf(bf2f((u16)v[j]) * scale);
  } else {
    int j0 = c * 8 - 128;
    bool lo = j0 < 32;
    int jj0 = lo ? j0 : j0 - 32;
    s16x8 a = *reinterpret_cast<const s16x8*>(qrow + 128 + 2 * jj0);
    s16x8 b = *reinterpret_cast<const s16x8*>(qrow + 128 + 2 * jj0 + 8);
    float4 c0 = *reinterpret_cast<const float4*>(cost + s * 32 + jj0);
    float4 c1 = *reinterpret_cast<const float4*>(cost + s * 32 + jj0 + 4);
    float4 s0 = *reinterpret_cast<const float4*>(sint + s * 32 + jj0);
    float4 s1 = *reinterpret_cast<const float4*>(sint + s * 32 + jj0 + 4);
    float cs[8] = {c0.x, c0.y, c0.z, c0.w, c1.x, c1.y, c1.z, c1.w};
    float sn[8] = {s0.x, s0.y, s0.z, s0.w, s1.x, s1.y, s1.z, s1.w};
#pragma unroll
    for (int j = 0; j < 8; ++j) {
      float x0 = bf2f((u16)((j < 4) ? a[2 * j] : b[2 * j - 8]));
      float x1 = bf2f((u16)((j < 4) ? a[2 * j + 1] : b[2 * j - 7]));
      float v = lo ? (x0 * cs[j] - x1 * sn[j]) : (x1 * cs[j] + x0 * sn[j]);
      out[j] = (short)f2bf(v * scale);
    }
  }
  *reinterpret_cast<s16x8*>(qf + o8) = out;
}

// ---------------- kf build (vectorized): kv [s][h*256], ckv(stride 2112) -> kf [h][s][192] ----------------
__global__ __launch_bounds__(256) void build_kf_kernel(const u16* __restrict__ kv,
                                                       const u16* __restrict__ ckv,
                                                       const float* __restrict__ cost,
                                                       const float* __restrict__ sint,
                                                       u16* __restrict__ kf) {
  int tid = blockIdx.x * 256 + threadIdx.x;
  int o8 = tid * 8;
  if (o8 >= 32 * 2048 * 192) return;
  int c = (o8 % 192) >> 3;
  int rest = o8 / 192;
  int s = rest & 2047, h = rest >> 11;
  s16x8 out;
  if (c < 16) {
    out = *reinterpret_cast<const s16x8*>(kv + ((size_t)s * 32 + h) * 256 + c * 8);
  } else {
    int j0 = c * 8 - 128;
    bool lo = j0 < 32;
    int jj0 = lo ? j0 : j0 - 32;
    const u16* crow = ckv + (size_t)s * 2112 + 512;
    s16x8 a = *reinterpret_cast<const s16x8*>(crow + 2 * jj0);
    s16x8 b = *reinterpret_cast<const s16x8*>(crow + 2 * jj0 + 8);
    float4 c0 = *reinterpret_cast<const float4*>(cost + s * 32 + jj0);
    float4 c1 = *reinterpret_cast<const float4*>(cost + s * 32 + jj0 + 4);
    float4 s0 = *reinterpret_cast<const float4*>(sint + s * 32 + jj0);
    float4 s1 = *reinterpret_cast<const float4*>(sint + s * 32 + jj0 + 4);
    float cs[8] = {c0.x, c0.y, c0.z, c0.w, c1.x, c1.y, c1.z, c1.w};
    float sn[8] = {s0.x, s0.y, s0.z, s0.w, s1.x, s1.y, s1.z, s1.w};
#pragma unroll
    for (int j = 0; j < 8; ++j) {
      float x0 = bf2f((u16)((j < 4) ? a[2 * j] : b[2 * j - 8]));
      float x1 = bf2f((u16)((j < 4) ? a[2 * j + 1] : b[2 * j - 7]));
      float v = lo ? (x0 * cs[j] - x1 * sn[j]) : (x1 * cs[j] + x0 * sn[j]);
      out[j] = (short)f2bf(v);
    }
  }
  *reinterpret_cast<s16x8*>(kf + o8) = out;
}

// ---------------- vT build: kv [s][h*256+128+d] -> vT [h][128][2048] ----------------
__global__ __launch_bounds__(256) void vt_build_kernel(const u16* __restrict__ kv,
                                                       u16* __restrict__ vT) {
  __shared__ u16 tile[64][72];
  const int t = threadIdx.x;
  const int sb = blockIdx.x * 64, db = blockIdx.y * 64, h = blockIdx.z;
  const int rr = t >> 3, cc = (t & 7) * 8;
#pragma unroll
  for (int pass = 0; pass < 2; ++pass) {
    const u16* src = kv + (size_t)(sb + pass * 32 + rr) * 8192 + h * 256 + 128 + db + cc;
    s16x8 v = *reinterpret_cast<const s16x8*>(src);
#pragma unroll
    for (int j = 0; j < 8; ++j) tile[pass * 32 + rr][cc + j] = (u16)v[j];
  }
  __syncthreads();
#pragma unroll
  for (int pass = 0; pass < 2; ++pass) {
    s16x8 v;
#pragma unroll
    for (int j = 0; j < 8; ++j) v[j] = (short)tile[cc + j][pass * 32 + rr];
    *reinterpret_cast<s16x8*>(vT + ((size_t)h * 128 + db + pass * 32 + rr) * 2048 + sb + cc) = v;
  }
}

// ---------------- GEMM v3: C[M][N] = A[M][K](bf16) * BT[N][K](bf16)^T ----------------
// 128x128 tile, BK=32, 4 waves (2x2). 4-deep LDS pipeline, prefetch distance 3,
// one raw s_barrier/iter with counted vmcnt(8), XOR-swizzled LDS, setprio MFMA.
template <int OUT_BF16>
__global__ __launch_bounds__(256) void gemm_v3_kernel(const u16* __restrict__ A,
                                                      const u16* __restrict__ BT,
                                                      void* __restrict__ Cv,
                                                      int M, int N, int K) {
  __shared__ __align__(16) u16 S[4 * 8192];
  const int t0 = threadIdx.x;
  const int lane = t0 & 63, wave = t0 >> 6;
  const int wr = wave >> 1, wc = wave & 1;
  const int row0 = blockIdx.y * 128, col0 = blockIdx.x * 128;
  const int lrow = lane & 15, lkg = lane >> 4;

  const int lp = lane ^ ((lane >> 3) & 3);
  const int srow_off = lp >> 2;
  const int skel = (lp & 3) * 8;
  const int c0 = wave * 2, c1 = c0 + 1;
  const int arow_c0 = row0 + c0 * 16 + srow_off;
  const int arow_c1 = row0 + c1 * 16 + srow_off;
  int brow_c0 = col0 + c0 * 16 + srow_off; if (brow_c0 > N - 1) brow_c0 = N - 1;
  int brow_c1 = col0 + c1 * 16 + srow_off; if (brow_c1 > N - 1) brow_c1 = N - 1;

  int aoff[4], boff[4];
#pragma unroll
  for (int m = 0; m < 4; ++m) {
    int r = wr * 64 + m * 16 + lrow;
    int off = r * 32 + lkg * 8;
    aoff[m] = off ^ ((off >> 3) & 0x18);
    r = wc * 64 + m * 16 + lrow;
    off = r * 32 + lkg * 8;
    boff[m] = off ^ ((off >> 3) & 0x18);
  }

  const int NT = K >> 5;

#pragma unroll
  for (int pt = 0; pt < 3; ++pt) {
    u16* ab = &S[pt * 8192];
    const int kb = pt * 32 + skel;
    gload16(A  + (size_t)arow_c0 * K + kb, ab + c0 * 512);
    gload16(A  + (size_t)arow_c1 * K + kb, ab + c1 * 512);
    gload16(BT + (size_t)brow_c0 * K + kb, ab + 4096 + c0 * 512);
    gload16(BT + (size_t)brow_c1 * K + kb, ab + 4096 + c1 * 512);
  }

  f32x4 acc[4][4];
#pragma unroll
  for (int m = 0; m < 4; ++m)
#pragma unroll
    for (int n = 0; n < 4; ++n) acc[m][n] = 0.f;

  for (int t = 0; t < NT; ++t) {
    if (t + 2 < NT)      asm volatile("s_waitcnt vmcnt(8)" ::: "memory");
    else if (t + 1 < NT) asm volatile("s_waitcnt vmcnt(4)" ::: "memory");
    else                 asm volatile("s_waitcnt vmcnt(0)" ::: "memory");
    __builtin_amdgcn_s_barrier();
    __builtin_amdgcn_sched_barrier(0);

    const u16* ab = &S[(t & 3) * 8192];
    bf16x8 af[4], bb[4];
#pragma unroll
    for (int m = 0; m < 4; ++m)
      af[m] = *reinterpret_cast<const bf16x8*>(ab + aoff[m]);
#pragma unroll
    for (int n = 0; n < 4; ++n)
      bb[n] = *reinterpret_cast<const bf16x8*>(ab + 4096 + boff[n]);

    if (t + 3 < NT) {
      u16* sb = &S[((t + 3) & 3) * 8192];
      const int kb = (t + 3) * 32 + skel;
      gload16(A  + (size_t)arow_c0 * K + kb, sb + c0 * 512);
      gload16(A  + (size_t)arow_c1 * K + kb, sb + c1 * 512);
      gload16(BT + (size_t)brow_c0 * K + kb, sb + 4096 + c0 * 512);
      gload16(BT + (size_t)brow_c1 * K + kb, sb + 4096 + c1 * 512);
    }

    __builtin_amdgcn_s_setprio(1);
#pragma unroll
    for (int m = 0; m < 4; ++m)
#pragma unroll
      for (int n = 0; n < 4; ++n)
        acc[m][n] = __builtin_amdgcn_mfma_f32_16x16x32_bf16(af[m], bb[n], acc[m][n], 0, 0, 0);
    __builtin_amdgcn_s_setprio(0);
  }

#pragma unroll
  for (int m = 0; m < 4; ++m) {
#pragma unroll
    for (int n = 0; n < 4; ++n) {
      int col = col0 + wc * 64 + n * 16 + lrow;
      if (col < N) {
#pragma unroll
        for (int i = 0; i < 4; ++i) {
          int row = row0 + wr * 64 + m * 16 + lkg * 4 + i;
          size_t idx = (size_t)row * N + col;
          if (OUT_BF16) ((u16*)Cv)[idx] = f2bf(acc[m][n][i]);
          else          ((float*)Cv)[idx] = acc[m][n][i];
        }
      }
    }
  }
}

// ---------------- causal flash attention (round-6 geometry + defer-max + deferred-l) ----------------
// grid (h=32, pair=16): bid%8 = h%8 pins each head's K/V to one XCD L2.
// 512 blocks = 2/CU (cross-block overlap hides staging). Block handles qb=pair
// and qb=31-pair (constant 33 KV-64 iterations). 256 thr = 4 waves; wave w owns
// q rows qb*64+w*16..+16. K/V staged to LDS in fragment order via global_load_lds.
// VALU cuts: T13 defer-max (rescale only when __any(tmax > m_run+8); P <= e^8,
// f32 acc tolerates) + deferred-l (per-lane partial l, one epilogue reduce;
// exact since m is uniform across each 16-lane row-group).
__global__ __launch_bounds__(256) void mla_attn_kernel(const u16* __restrict__ qf,
                                                       const u16* __restrict__ kf,
                                                       const u16* __restrict__ vT,
                                                       u16* __restrict__ o) {
  const int h = blockIdx.x, pair = blockIdx.y;
  const int t = threadIdx.x, wave = t >> 6, lane = t & 63;
  const int lrow = lane & 15, lkg = lane >> 4;
  __shared__ __align__(16) u16 Kt[24 * 512];   // (cg,kk): K[cg*16+l&15][kk*32+(l>>4)*8]
  __shared__ __align__(16) u16 Vt[16 * 512];   // (f,ck):  vT[f*16+l&15][ck*32+(l>>4)*8]
  __shared__ __align__(16) u16 Pl[4][16][72];

  const u16* ksrc0 = kf + ((size_t)h * 2048 + wave * 16 + lrow) * 192 + lkg * 8;
  const u16* vsrc0 = vT + ((size_t)h * 128 + wave * 32 + lrow) * 2048 + lkg * 8;

  for (int qq = 0; qq < 2; ++qq) {
    const int qb = qq ? (31 - pair) : pair;
    const int qbase = qb * 64 + wave * 16;

    bf16x8 qfr[6];
    const u16* qrow_ptr = qf + ((size_t)h * 2048 + qbase + lrow) * 192;
#pragma unroll
    for (int kk = 0; kk < 6; ++kk)
      qfr[kk] = *reinterpret_cast<const bf16x8*>(qrow_ptr + kk * 32 + lkg * 8);

    f32x4 acc_o[8];
#pragma unroll
    for (int f = 0; f < 8; ++f) acc_o[f] = 0.f;
    float m_run[4], l_par[4];
#pragma unroll
    for (int i = 0; i < 4; ++i) { m_run[i] = -1e30f; l_par[i] = 0.f; }

    const int kv_end = qb * 64 + 64;
    for (int kt = 0; kt < kv_end; kt += 64) {
      {
        const u16* ks = ksrc0 + (size_t)kt * 192;
#pragma unroll
        for (int kk = 0; kk < 6; ++kk)
          gload16(ks + kk * 32, &Kt[(wave * 6 + kk) * 512]);
#pragma unroll
        for (int j = 0; j < 4; ++j) {
          int fo = (j >> 1), ck = j & 1;
          gload16(vsrc0 + (size_t)fo * 16 * 2048 + kt + ck * 32,
                  &Vt[((wave * 2 + fo) * 2 + ck) * 512]);
        }
      }
      __syncthreads();

      f32x4 sv[4];
#pragma unroll
      for (int cg = 0; cg < 4; ++cg) sv[cg] = 0.f;
#pragma unroll
      for (int cg = 0; cg < 4; ++cg)
#pragma unroll
        for (int kk = 0; kk < 6; ++kk) {
          bf16x8 kfr = *reinterpret_cast<const bf16x8*>(&Kt[(cg * 6 + kk) * 512 + lane * 8]);
          sv[cg] = __builtin_amdgcn_mfma_f32_16x16x32_bf16(qfr[kk], kfr, sv[cg], 0, 0, 0);
        }

      const int qrow_b = qbase + lkg * 4;
      if (kt + 64 >= kv_end) {
#pragma unroll
        for (int cg = 0; cg < 4; ++cg) {
          int kvcol = kt + cg * 16 + lrow;
#pragma unroll
          for (int i = 0; i < 4; ++i)
            if (kvcol > qrow_b + i) sv[cg][i] = -__builtin_inff();
        }
      }
      // ---- softmax: defer-max + deferred-l ----
      float tmax[4];
#pragma unroll
      for (int i = 0; i < 4; ++i)
        tmax[i] = fmaxf(fmaxf(sv[0][i], sv[1][i]), fmaxf(sv[2][i], sv[3][i]));
#pragma unroll
      for (int m = 8; m >= 1; m >>= 1)
#pragma unroll
        for (int i = 0; i < 4; ++i) tmax[i] = fmaxf(tmax[i], __shfl_xor(tmax[i], m));
      int need = 0;
#pragma unroll
      for (int i = 0; i < 4; ++i) need |= (tmax[i] > m_run[i] + 8.f) ? 1 : 0;
      if (__any(need)) {
#pragma unroll
        for (int i = 0; i < 4; ++i) {
          float mnew = fmaxf(m_run[i], tmax[i]);
          float alpha = __expf(m_run[i] - mnew);
          m_run[i] = mnew;
          l_par[i] *= alpha;
#pragma unroll
          for (int f = 0; f < 8; ++f) acc_o[f][i] *= alpha;
        }
      }
#pragma unroll
      for (int i = 0; i < 4; ++i) {
#pragma unroll
        for (int cg = 0; cg < 4; ++cg) sv[cg][i] = __expf(sv[cg][i] - m_run[i]);
        l_par[i] += (sv[0][i] + sv[1][i]) + (sv[2][i] + sv[3][i]);
      }
      // ---- P -> bf16 -> per-wave LDS ----
#pragma unroll
      for (int cg = 0; cg < 4; ++cg)
#pragma unroll
        for (int i = 0; i < 4; ++i)
          Pl[wave][lkg * 4 + i][cg * 16 + lrow] = f2bf(sv[cg][i]);
      // ---- O += P V (V from LDS) ----
#pragma unroll
      for (int ck = 0; ck < 2; ++ck) {
        bf16x8 pf = *reinterpret_cast<const bf16x8*>(&Pl[wave][lrow][ck * 32 + lkg * 8]);
#pragma unroll
        for (int f = 0; f < 8; ++f) {
          bf16x8 vfr = *reinterpret_cast<const bf16x8*>(&Vt[(f * 2 + ck) * 512 + lane * 8]);
          acc_o[f] = __builtin_amdgcn_mfma_f32_16x16x32_bf16(pf, vfr, acc_o[f], 0, 0, 0);
        }
      }
      __syncthreads();
    }
    // ---- epilogue: one l reduce, divide, store ----
#pragma unroll
    for (int i = 0; i < 4; ++i)
#pragma unroll
      for (int m = 8; m >= 1; m >>= 1) l_par[i] += __shfl_xor(l_par[i], m);
#pragma unroll
    for (int f = 0; f < 8; ++f)
#pragma unroll
      for (int i = 0; i < 4; ++i) {
        int row = qbase + lkg * 4 + i;
        int col = h * 128 + f * 16 + lrow;
        o[(size_t)row * 4096 + col] = f2bf(acc_o[f][i] / l_par[i]);
      }
  }
}

// ---------------------------------------------------------------
extern "C" void kernel_launch(void* const* d_in, const int* in_sizes, int n_in,
                              void* d_out, int out_size, void* d_ws, size_t ws_size,
                              hipStream_t stream) {
  (void)in_sizes; (void)n_in; (void)out_size; (void)ws_size;
  const float* hs   = (const float*)d_in[0];
  const float* Wqa  = (const float*)d_in[1];
  const float* qln  = (const float*)d_in[2];
  const float* Wqb  = (const float*)d_in[3];
  const float* Wkva = (const float*)d_in[4];
  const float* kvln = (const float*)d_in[5];
  const float* Wkvb = (const float*)d_in[6];
  const float* Wo   = (const float*)d_in[7];
  float* out = (float*)d_out;

  char* p = (char*)d_ws;
  size_t off = 0;
  auto carve = [&](size_t bytes) {
    char* r = p + off;
    off += (bytes + 255) & ~(size_t)255;
    return r;
  };
  u16* hs_bf = (u16*)carve((size_t)2048 * 4096 * 2);
  u16* WabT  = (u16*)carve((size_t)2112 * 4096 * 2);   // [0..1535]=WqaT, [1536..2111]=WkvaT
  u16* WqbT  = (u16*)carve((size_t)6144 * 1536 * 2);
  u16* WkvbT = (u16*)carve((size_t)8192 * 512 * 2);
  u16* WoT   = (u16*)carve((size_t)4096 * 4096 * 2);
  u16* fused = (u16*)carve((size_t)2048 * 2112 * 2);   // [qa | ckv] per row
  u16* qan   = (u16*)carve((size_t)2048 * 1536 * 2);
  u16* q     = (u16*)carve((size_t)2048 * 6144 * 2);
  u16* cn    = (u16*)carve((size_t)2048 * 512 * 2);
  u16* kv    = (u16*)carve((size_t)2048 * 8192 * 2);
  u16* qfb   = (u16*)carve((size_t)32 * 2048 * 192 * 2);
  u16* kfb   = (u16*)carve((size_t)32 * 2048 * 192 * 2);
  u16* vTb   = (u16*)carve((size_t)32 * 128 * 2048 * 2);
  u16* ob    = (u16*)carve((size_t)2048 * 4096 * 2);
  float* cost = (float*)carve((size_t)65536 * 4);
  float* sint = (float*)carve((size_t)65536 * 4);

  // --- prep: casts / transposes / tables ---
  cast_bf16_kernel<<<8192, 256, 0, stream>>>(hs, hs_bf, 2048 * 4096);
  transpose_cast_kernel<<<dim3(24, 64), 256, 0, stream>>>(Wqa, WabT, 4096, 1536);
  transpose_cast_kernel<<<dim3(9, 64), 256, 0, stream>>>(Wkva, WabT + (size_t)1536 * 4096, 4096, 576);
  transpose_cast_kernel<<<dim3(96, 24), 256, 0, stream>>>(Wqb, WqbT, 1536, 6144);
  transpose_cast_kernel<<<dim3(128, 8), 256, 0, stream>>>(Wkvb, WkvbT, 512, 8192);
  transpose_cast_kernel<<<dim3(64, 64), 256, 0, stream>>>(Wo, WoT, 4096, 4096);
  rope_table_kernel<<<256, 256, 0, stream>>>(cost, sint);

  // --- fused first-stage GEMM: [qa | ckv] = hs @ [Wqa | Wkva] ---
  gemm_v3_kernel<1><<<dim3(17, 16), 256, 0, stream>>>(hs_bf, WabT, fused, 2048, 2112, 4096);

  // --- norms ---
  rmsnorm_kernel<<<2048, 256, 0, stream>>>(fused, qln, qan, 1536, 2112, 1536);
  rmsnorm_kernel<<<2048, 256, 0, stream>>>(fused + 1536, kvln, cn, 512, 2112, 512);

  // --- second-stage GEMMs ---
  gemm_v3_kernel<1><<<dim3(48, 16), 256, 0, stream>>>(qan, WqbT, q, 2048, 6144, 1536);
  gemm_v3_kernel<1><<<dim3(64, 16), 256, 0, stream>>>(cn, WkvbT, kv, 2048, 8192, 512);

  // --- head-major layouts + RoPE (vectorized) ---
  build_qf_kernel<<<6144, 256, 0, stream>>>(q, cost, sint, qfb);
  build_kf_kernel<<<6144, 256, 0, stream>>>(kv, fused + 1536, cost, sint, kfb);
  vt_build_kernel<<<dim3(32, 2, 32), 256, 0, stream>>>(kv, vTb);

  // --- attention (512 blocks, 2/CU, head-pinned XCD, paired) ---
  mla_attn_kernel<<<dim3(32, 16), 256, 0, stream>>>(qfb, kfb, vTb, ob);

  // --- output projection ---
  gemm_v3_kernel<0><<<dim3(32, 16), 256, 0, stream>>>(ob, WoT, out, 2048, 4096, 4096);
}